// Round 6
// baseline (116.457 us; speedup 1.0000x reference)
//
#include <hip/hip_runtime.h>
#include <type_traits>

typedef unsigned short u16;
typedef __attribute__((ext_vector_type(8))) short short8;
typedef __attribute__((ext_vector_type(4))) float floatx4;

__device__ __forceinline__ u16 f2u(float f) {
  unsigned int x = __float_as_uint(f);
  x += 0x7fff + ((x >> 16) & 1);  // RNE to bf16
  return (u16)(x >> 16);
}

__device__ __forceinline__ void async16(const void* g, void* l) {
  __builtin_amdgcn_global_load_lds(
      (const __attribute__((address_space(1))) unsigned int*)g,
      (__attribute__((address_space(3))) unsigned int*)l, 16, 0, 0);
}

// Transpose+cast, one dispatch, two jobs decoded from blockIdx.x:
//  b < 1024 : U[2048][2048] fp32 -> Ut (transposed bf16) + Ubf (straight bf16)
//  b < 1152 : x[2048][256]  fp32 -> xT[256][2048] bf16
__global__ __launch_bounds__(256) void prep_kernel(
    const float* __restrict__ U, const float* __restrict__ x,
    u16* __restrict__ Ut, u16* __restrict__ Ubf, u16* __restrict__ xT,
    int N, int F) {
  __shared__ __attribute__((aligned(16))) float tile[64][65];
  int bb = blockIdx.x;
  int t = threadIdx.x;

  const float* in;
  u16 *outT, *outC;
  int R, C, c0, r0;
  if (bb < 1024) {  // U job
    in = U; outT = Ut; outC = Ubf; R = N; C = N;
    c0 = (bb & 31) * 64; r0 = (bb >> 5) * 64;
  } else {  // x job
    int b2 = bb - 1024;
    in = x; outT = xT; outC = nullptr; R = N; C = F;
    c0 = (b2 & 3) * 64; r0 = (b2 >> 2) * 64;
  }

#pragma unroll
  for (int p = 0; p < 4; ++p) {
    int e = p * 256 + t;
    int row = e >> 4, col = (e & 15) * 4;
    float4 v = *(const float4*)(in + (size_t)(r0 + row) * C + c0 + col);
    tile[row][col] = v.x;
    tile[row][col + 1] = v.y;
    tile[row][col + 2] = v.z;
    tile[row][col + 3] = v.w;
    if (outC) {
      union { uint2 u; u16 s[4]; } pk;
      pk.s[0] = f2u(v.x); pk.s[1] = f2u(v.y);
      pk.s[2] = f2u(v.z); pk.s[3] = f2u(v.w);
      *(uint2*)(outC + (size_t)(r0 + row) * C + c0 + col) = pk.u;
    }
  }
  __syncthreads();
#pragma unroll
  for (int p = 0; p < 2; ++p) {
    int e = p * 256 + t;
    int orow = e >> 3, oc = (e & 7) * 8;
    union { uint4 v; u16 s[8]; } tmp;
#pragma unroll
    for (int i = 0; i < 8; ++i) tmp.s[i] = f2u(tile[oc + i][orow]);
    *(uint4*)(outT + (size_t)(c0 + orow) * R + r0 + oc) = tmp.v;
  }
}

// Direct TN GEMM with wave-level K-split: C[m][col] = sum_k A[m][k]*B[col][k]
// A: [M][K] bf16 (k contig). B: [NN][K] bf16 (k contig). BM=BN=32.
// 4 waves; macro BK=128 staged as 4 k32-subtiles (dbuf). Wave w consumes
// ONLY subtile w each macro, computing the full 32x32 tile as 2x2 MFMAs
// over its K-slice -> every LDS byte read exactly once (4x less than all-
// waves-read-all). fp32 partials reduced across waves via LDS in epilogue.
// SCALE_D: *= d(col) computed inline from lam/pa/pb/pc.
// RESIDUAL: += alpha_p[0]*resid[idx] (fp32).
template <bool SCALE_D, bool RESIDUAL, typename CT>
__global__ __launch_bounds__(256) void gemm32ks(
    const u16* __restrict__ A, const u16* __restrict__ B, CT* __restrict__ C,
    int M, int NN, int K, const float* __restrict__ lam,
    const float* __restrict__ pa, const float* __restrict__ pb,
    const float* __restrict__ pc, const float* __restrict__ resid,
    const float* __restrict__ alpha_p) {
  __shared__ __attribute__((aligned(16))) u16 lA[2 * 4096];   // 16 KB
  __shared__ __attribute__((aligned(16))) u16 lB[2 * 4096];   // 16 KB
  __shared__ __attribute__((aligned(16))) float accf[4 * 1024];  // 16 KB
  const int m0 = blockIdx.x * 32;
  const int n0 = blockIdx.y * 32;
  const int t = threadIdx.x;
  const int wave = t >> 6, lane = t & 63;
  const int q = lane >> 4, l15 = lane & 15;

  // Staging (as round 5): thread t moves 16B chunks t and t+256 of each
  // 8KB macro-slab; LDS dest = base + t*16 (wave-uniform + lane*16).
  const int within = t & 127, st0 = t >> 7;  // st0 in {0,1}
  const u16* gA = A + (size_t)(m0 + (within >> 2)) * K + (within & 3) * 8;
  const u16* gB = B + (size_t)(n0 + (within >> 2)) * K + (within & 3) * 8;
  char* lAc = (char*)lA;
  char* lBc = (char*)lB;

  const int NM = K >> 7;  // macro-iters (K/128)

  auto issue = [&](int i, int buf) {
    int k0 = i * 128;
    async16(gA + k0 + st0 * 32, lAc + buf * 8192 + t * 16);
    async16(gA + k0 + (st0 + 2) * 32, lAc + buf * 8192 + 4096 + t * 16);
    async16(gB + k0 + st0 * 32, lBc + buf * 8192 + t * 16);
    async16(gB + k0 + (st0 + 2) * 32, lBc + buf * 8192 + 4096 + t * 16);
  };

  floatx4 acc[2][2];
#pragma unroll
  for (int i = 0; i < 2; ++i)
#pragma unroll
    for (int j = 0; j < 2; ++j) acc[i][j] = (floatx4){0.f, 0.f, 0.f, 0.f};

  issue(0, 0);
  for (int i = 0; i < NM; ++i) {
    const int buf = i & 1;
    __syncthreads();  // drains buf's prefetch; all waves done with buf^1
    if (i + 1 < NM) issue(i + 1, buf ^ 1);
    // wave's private k32-subtile of this macro
    const u16* lAb = lA + buf * 4096 + wave * 1024;
    const u16* lBb = lB + buf * 4096 + wave * 1024;
    short8 a0 = *(const short8*)&lAb[l15 * 32 + q * 8];
    short8 a1 = *(const short8*)&lAb[(16 + l15) * 32 + q * 8];
    short8 b0 = *(const short8*)&lBb[l15 * 32 + q * 8];
    short8 b1 = *(const short8*)&lBb[(16 + l15) * 32 + q * 8];
    acc[0][0] = __builtin_amdgcn_mfma_f32_16x16x32_bf16(a0, b0, acc[0][0], 0, 0, 0);
    acc[0][1] = __builtin_amdgcn_mfma_f32_16x16x32_bf16(a0, b1, acc[0][1], 0, 0, 0);
    acc[1][0] = __builtin_amdgcn_mfma_f32_16x16x32_bf16(a1, b0, acc[1][0], 0, 0, 0);
    acc[1][1] = __builtin_amdgcn_mfma_f32_16x16x32_bf16(a1, b1, acc[1][1], 0, 0, 0);
  }

  // Dump partials: C/D layout col=lane&15, row=(lane>>4)*4+reg  [m89/m91]
  __syncthreads();  // last macro's ds_reads complete everywhere
#pragma unroll
  for (int mt = 0; mt < 2; ++mt)
#pragma unroll
    for (int nt = 0; nt < 2; ++nt)
#pragma unroll
      for (int r = 0; r < 4; ++r)
        accf[wave * 1024 + (mt * 16 + q * 4 + r) * 32 + nt * 16 + l15] =
            acc[mt][nt][r];
  __syncthreads();

  // Reduce 4 waves' partials; thread t owns elements e = t*4 .. t*4+3
  // (row = e>>5, cols (e&31)..+3) -> coalesced stores.
  const int e = t * 4;
  float4 s0 = *(const float4*)&accf[e];
  float4 s1 = *(const float4*)&accf[1024 + e];
  float4 s2 = *(const float4*)&accf[2048 + e];
  float4 s3 = *(const float4*)&accf[3072 + e];
  float v[4] = {s0.x + s1.x + s2.x + s3.x, s0.y + s1.y + s2.y + s3.y,
                s0.z + s1.z + s2.z + s3.z, s0.w + s1.w + s2.w + s3.w};
  const int row = e >> 5, colb = e & 31;
  const size_t base = (size_t)(m0 + row) * NN + n0 + colb;
  if (SCALE_D) {
#pragma unroll
    for (int j = 0; j < 4; ++j) {
      int col = n0 + colb + j;
      float lv = lam[(size_t)col * NN + col];
      float dacc = 0.f;
#pragma unroll
      for (int i = 0; i < 4; ++i) {
        float ai = pa[i], bi = pb[i], ci = pc[i];
        float rep = (ai - lv) * (lv - bi);
        rep = rep > 0.f ? rep : 0.f;
        dacc += ci * 4.f / ((ai - bi) * (ai - bi)) * rep;
      }
      v[j] *= dacc;
    }
  }
  if (RESIDUAL) {
    float alpha = alpha_p[0];
    float4 rx = *(const float4*)(resid + base);
    v[0] += alpha * rx.x; v[1] += alpha * rx.y;
    v[2] += alpha * rx.z; v[3] += alpha * rx.w;
  }
  if constexpr (std::is_same<CT, u16>::value) {
    union { uint2 u; u16 s[4]; } pk;
    pk.s[0] = f2u(v[0]); pk.s[1] = f2u(v[1]);
    pk.s[2] = f2u(v[2]); pk.s[3] = f2u(v[3]);
    *(uint2*)(C + base) = pk.u;
  } else {
    float4 o = {v[0], v[1], v[2], v[3]};
    *(float4*)(C + base) = o;
  }
}

extern "C" void kernel_launch(void* const* d_in, const int* in_sizes, int n_in,
                              void* d_out, int out_size, void* d_ws,
                              size_t ws_size, hipStream_t stream) {
  const int N = 2048, F = 256;
  const float* x = (const float*)d_in[0];     // [N][F] fp32
  const float* lam = (const float*)d_in[1];   // [N][N] fp32 (diag)
  const float* U = (const float*)d_in[2];     // [N][N] fp32
  const float* a = (const float*)d_in[3];
  const float* b = (const float*)d_in[4];
  const float* c = (const float*)d_in[5];
  const float* alpha = (const float*)d_in[6];
  // d_in[7] = edge_index: unused by the reference math

  char* ws = (char*)d_ws;
  u16* xT = (u16*)ws;                          // [F][N] bf16 1 MB
  u16* Ut = (u16*)(ws + (1 << 20));            // [N][N] bf16 (U^T) 8 MB
  u16* Ubf = (u16*)(ws + (9 << 20));           // [N][N] bf16 8 MB
  u16* zT = (u16*)(ws + (17 << 20));           // [F][N] bf16 1 MB

  // prep: Ut + Ubf + xT in one dispatch
  prep_kernel<<<1152, 256, 0, stream>>>(U, x, Ut, Ubf, xT, N, F);
  // GEMM1: zT[f][j] = d[j] * sum_n xT[f][n]*Ut[j][n]   (bf16 out)
  gemm32ks<true, false, u16><<<dim3(F / 32, N / 32), 256, 0, stream>>>(
      xT, Ut, zT, F, N, N, lam, a, b, c, nullptr, nullptr);
  // GEMM2: out[n][f] = alpha*x[n][f] + sum_j Ubf[n][j]*zT[f][j]  (fp32 out)
  gemm32ks<false, true, float><<<dim3(N / 32, F / 32), 256, 0, stream>>>(
      Ubf, zT, (float*)d_out, N, F, N, nullptr, nullptr, nullptr, nullptr,
      x, alpha);
}

// Round 7
// 109.833 us; speedup vs baseline: 1.0603x; 1.0603x over previous
//
#include <hip/hip_runtime.h>
#include <type_traits>

typedef unsigned short u16;
typedef __attribute__((ext_vector_type(8))) short short8;
typedef __attribute__((ext_vector_type(4))) float floatx4;

__device__ __forceinline__ u16 f2u(float f) {
  unsigned int x = __float_as_uint(f);
  x += 0x7fff + ((x >> 16) & 1);  // RNE to bf16
  return (u16)(x >> 16);
}

__device__ __forceinline__ void async16(const void* g, void* l) {
  __builtin_amdgcn_global_load_lds(
      (const __attribute__((address_space(1))) unsigned int*)g,
      (__attribute__((address_space(3))) unsigned int*)l, 16, 0, 0);
}

// Transpose+cast, one dispatch, two jobs decoded from blockIdx.x:
//  b < 1024 : U[2048][2048] fp32 -> Ut (transposed bf16) + Ubf (straight bf16)
//  b < 1152 : x[2048][256]  fp32 -> xT[256][2048] bf16
__global__ __launch_bounds__(256) void prep_kernel(
    const float* __restrict__ U, const float* __restrict__ x,
    u16* __restrict__ Ut, u16* __restrict__ Ubf, u16* __restrict__ xT,
    int N, int F) {
  __shared__ __attribute__((aligned(16))) float tile[64][65];
  int bb = blockIdx.x;
  int t = threadIdx.x;

  const float* in;
  u16 *outT, *outC;
  int R, C, c0, r0;
  if (bb < 1024) {  // U job
    in = U; outT = Ut; outC = Ubf; R = N; C = N;
    c0 = (bb & 31) * 64; r0 = (bb >> 5) * 64;
  } else {  // x job
    int b2 = bb - 1024;
    in = x; outT = xT; outC = nullptr; R = N; C = F;
    c0 = (b2 & 3) * 64; r0 = (b2 >> 2) * 64;
  }

#pragma unroll
  for (int p = 0; p < 4; ++p) {
    int e = p * 256 + t;
    int row = e >> 4, col = (e & 15) * 4;
    float4 v = *(const float4*)(in + (size_t)(r0 + row) * C + c0 + col);
    tile[row][col] = v.x;
    tile[row][col + 1] = v.y;
    tile[row][col + 2] = v.z;
    tile[row][col + 3] = v.w;
    if (outC) {
      union { uint2 u; u16 s[4]; } pk;
      pk.s[0] = f2u(v.x); pk.s[1] = f2u(v.y);
      pk.s[2] = f2u(v.z); pk.s[3] = f2u(v.w);
      *(uint2*)(outC + (size_t)(r0 + row) * C + c0 + col) = pk.u;
    }
  }
  __syncthreads();
#pragma unroll
  for (int p = 0; p < 2; ++p) {
    int e = p * 256 + t;
    int orow = e >> 3, oc = (e & 7) * 8;
    union { uint4 v; u16 s[8]; } tmp;
#pragma unroll
    for (int i = 0; i < 8; ++i) tmp.s[i] = f2u(tile[oc + i][orow]);
    *(uint4*)(outT + (size_t)(c0 + orow) * R + r0 + oc) = tmp.v;
  }
}

// Direct TN GEMM: C[m][col] = sum_k A[m][k]*B[col][k]
// A: [M][K] bf16 (k contig). B: [NN][K] bf16 (k contig).
// BM=BN=32; 4 waves 2x2, each one 16x16 MFMA accumulator.
// Macro BK=256 (8 sub-tiles of 32), double-buffered LDS, ONE __syncthreads
// per macro-iter (8 total for K=2048 -- barrier drain is the binding cost,
// so minimize barrier count). Prefetch issued right after the barrier;
// latency hides behind this macro's 8x(2 ds_read_b128 + MFMA) plus the
// co-resident block (grid=512 -> 2 blocks/CU at 64KB LDS).
// SCALE_D: *= d(col) computed inline from lam/pa/pb/pc.
// RESIDUAL: += alpha_p[0]*resid[idx] (fp32).
template <bool SCALE_D, bool RESIDUAL, typename CT>
__global__ __launch_bounds__(256) void gemm32(
    const u16* __restrict__ A, const u16* __restrict__ B, CT* __restrict__ C,
    int M, int NN, int K, const float* __restrict__ lam,
    const float* __restrict__ pa, const float* __restrict__ pb,
    const float* __restrict__ pc, const float* __restrict__ resid,
    const float* __restrict__ alpha_p) {
  // per buf per operand: 8 subtiles x (32x32 u16, 2KB) = 16KB; x2 bufs.
  __shared__ __attribute__((aligned(16))) u16 lA[2 * 8192];  // 32 KB
  __shared__ __attribute__((aligned(16))) u16 lB[2 * 8192];  // 32 KB
  const int m0 = blockIdx.x * 32;
  const int n0 = blockIdx.y * 32;
  const int t = threadIdx.x;
  const int wave = t >> 6, lane = t & 63;
  const int wm = wave >> 1, wn = wave & 1;
  const int q = lane >> 4, l15 = lane & 15;

  // Staging: macro-slab per operand = 8 subtiles x 32 rows x 64B = 16KB
  // = 1024 x 16B chunks; thread t moves chunk p*256+t for p=0..3.
  // Subtile of chunk ch = ch>>7; within: row=(ch&127)>>2, c16=ch&3.
  // LDS dest = slab + ch*16 (wave-uniform base + lane*16 per pass).
  const int within = t & 127, st0 = t >> 7;  // st0 in {0,1}
  const u16* gA = A + (size_t)(m0 + (within >> 2)) * K + (within & 3) * 8;
  const u16* gB = B + (size_t)(n0 + (within >> 2)) * K + (within & 3) * 8;
  char* lAc = (char*)lA;
  char* lBc = (char*)lB;

  const int NM = K >> 8;  // macro-iters (K/256)

  auto issue = [&](int i, int buf) {
    int k0 = i * 256;
#pragma unroll
    for (int p = 0; p < 4; ++p) {
      int st = 2 * p + st0;
      async16(gA + k0 + st * 32, lAc + buf * 16384 + p * 4096 + t * 16);
      async16(gB + k0 + st * 32, lBc + buf * 16384 + p * 4096 + t * 16);
    }
  };

  floatx4 acc = (floatx4){0.f, 0.f, 0.f, 0.f};

  issue(0, 0);
  for (int i = 0; i < NM; ++i) {
    const int buf = i & 1;
    __syncthreads();  // drains buf's prefetch; all waves done with buf^1
    if (i + 1 < NM) issue(i + 1, buf ^ 1);
    const u16* lAb = lA + buf * 8192;  // u16 units
    const u16* lBb = lB + buf * 8192;
#pragma unroll
    for (int st = 0; st < 8; ++st) {
      short8 af = *(const short8*)&lAb[st * 1024 + (wm * 16 + l15) * 32 + q * 8];
      short8 bf = *(const short8*)&lBb[st * 1024 + (wn * 16 + l15) * 32 + q * 8];
      acc = __builtin_amdgcn_mfma_f32_16x16x32_bf16(af, bf, acc, 0, 0, 0);
    }
  }

  // C/D layout: col=lane&15, row=(lane>>4)*4+reg  [m89/m91]
  const int col = n0 + wn * 16 + l15;
  float ds = 1.f;
  if (SCALE_D) {
    // d(col) = sum_i 4*c_i/(a_i-b_i)^2 * relu((a_i-lv)(lv-b_i))
    float lv = lam[(size_t)col * NN + col];
    float dacc = 0.f;
#pragma unroll
    for (int i = 0; i < 4; ++i) {
      float ai = pa[i], bi = pb[i], ci = pc[i];
      float rep = (ai - lv) * (lv - bi);
      rep = rep > 0.f ? rep : 0.f;
      dacc += ci * 4.f / ((ai - bi) * (ai - bi)) * rep;
    }
    ds = dacc;
  }
  float alpha = 0.f;
  if (RESIDUAL) alpha = alpha_p[0];
  const int rbase = m0 + wm * 16 + q * 4;
#pragma unroll
  for (int r = 0; r < 4; ++r) {
    float v = acc[r];
    if (SCALE_D) v *= ds;
    size_t idx = (size_t)(rbase + r) * NN + col;
    if (RESIDUAL) v += alpha * resid[idx];
    if constexpr (std::is_same<CT, u16>::value)
      C[idx] = f2u(v);
    else
      C[idx] = v;
  }
}

extern "C" void kernel_launch(void* const* d_in, const int* in_sizes, int n_in,
                              void* d_out, int out_size, void* d_ws,
                              size_t ws_size, hipStream_t stream) {
  const int N = 2048, F = 256;
  const float* x = (const float*)d_in[0];     // [N][F] fp32
  const float* lam = (const float*)d_in[1];   // [N][N] fp32 (diag)
  const float* U = (const float*)d_in[2];     // [N][N] fp32
  const float* a = (const float*)d_in[3];
  const float* b = (const float*)d_in[4];
  const float* c = (const float*)d_in[5];
  const float* alpha = (const float*)d_in[6];
  // d_in[7] = edge_index: unused by the reference math

  char* ws = (char*)d_ws;
  u16* xT = (u16*)ws;                          // [F][N] bf16 1 MB
  u16* Ut = (u16*)(ws + (1 << 20));            // [N][N] bf16 (U^T) 8 MB
  u16* Ubf = (u16*)(ws + (9 << 20));           // [N][N] bf16 8 MB
  u16* zT = (u16*)(ws + (17 << 20));           // [F][N] bf16 1 MB

  // prep: Ut + Ubf + xT in one dispatch
  prep_kernel<<<1152, 256, 0, stream>>>(U, x, Ut, Ubf, xT, N, F);
  // GEMM1: zT[f][j] = d[j] * sum_n xT[f][n]*Ut[j][n]   (bf16 out)
  gemm32<true, false, u16><<<dim3(F / 32, N / 32), 256, 0, stream>>>(
      xT, Ut, zT, F, N, N, lam, a, b, c, nullptr, nullptr);
  // GEMM2: out[n][f] = alpha*x[n][f] + sum_j Ubf[n][j]*zT[f][j]  (fp32 out)
  gemm32<false, true, float><<<dim3(N / 32, F / 32), 256, 0, stream>>>(
      Ubf, zT, (float*)d_out, N, F, N, nullptr, nullptr, nullptr, nullptr,
      x, alpha);
}